// Round 3
// baseline (147.959 us; speedup 1.0000x reference)
//
#include <hip/hip_runtime.h>
#include <math.h>

#define NUM_CLASSES 80
#define C_CH (NUM_CLASSES + 1)

__device__ __forceinline__ float softplusf(float x) {
    return fmaxf(x, 0.f) + log1pf(expf(-fabsf(x)));
}
__device__ __forceinline__ float sigmoidf_(float x) {
    return 1.f / (1.f + expf(-x));
}

// ws layout (floats):
//   bgpart : (nbg4+nbg5) floats   -- per-block softplus(channel-0) plane sums
//   tpart  : nTblk*4 floats       -- {lb, lo, lc, n} per target-block
// All slots written unconditionally every call: no zeroing needed.

__global__ void fused_kernel(
    const float* __restrict__ cls_p4, const float* __restrict__ reg_p4,
    const float* __restrict__ cls_p5, const float* __restrict__ reg_p5,
    const int* __restrict__ t4_cls, const float* __restrict__ t4_box, const float* __restrict__ t4_mask,
    const int* __restrict__ t5_cls, const float* __restrict__ t5_box, const float* __restrict__ t5_mask,
    float* __restrict__ bgpart, float* __restrict__ tpart,
    int B, int T, int nbg4, int nbg5)
{
    const int tid = threadIdx.x;
    const int nbg = nbg4 + nbg5;

    if ((int)blockIdx.x < nbg) {
        // ---------- background role: plain plane sum of softplus(channel 0) ----------
        const int blk = blockIdx.x;
        float sp = 0.f;
        if (blk < nbg4) {
            int b = blk / 25, j = blk - b * 25;          // 6400/256 = 25 blocks/image
            int cell = j * 256 + tid;
            sp = softplusf(cls_p4[(size_t)b * (C_CH * 6400) + cell]);
        } else {
            int o = blk - nbg4;
            int b = o / 7, j = o - b * 7;                // ceil(1600/256) = 7 blocks/image
            int cell = j * 256 + tid;
            if (cell < 1600)
                sp = softplusf(cls_p5[(size_t)b * (C_CH * 1600) + cell]);
        }
        for (int off = 32; off > 0; off >>= 1) sp += __shfl_down(sp, off, 64);
        __shared__ float ss[4];
        if ((tid & 63) == 0) ss[tid >> 6] = sp;
        __syncthreads();
        if (tid == 0) bgpart[blockIdx.x] = ss[0] + ss[1] + ss[2] + ss[3];
        return;
    }

    // ---------- target role: 4 targets per block, one per wave ----------
    const int BT = B * T;
    const int wave = tid >> 6;
    const int lane = tid & 63;
    const int tg = ((int)blockIdx.x - nbg) * 4 + wave;

    float lb = 0.f, lo = 0.f, lcv = 0.f, msum = 0.f;

    if (tg < 2 * BT) {
        const int scale = (tg >= BT) ? 1 : 0;
        const int ti = scale ? tg - BT : tg;
        const int b = ti / T;

        const float* cls_p; const float* reg_p; const int* tc; const float* tb_; const float* tm;
        int H, W;
        if (!scale) { cls_p = cls_p4; reg_p = reg_p4; tc = t4_cls; tb_ = t4_box; tm = t4_mask; H = 80; W = 80; }
        else        { cls_p = cls_p5; reg_p = reg_p5; tc = t5_cls; tb_ = t5_box; tm = t5_mask; H = 40; W = 40; }
        const int HW = H * W;

        const float mask = tm[ti];
        const int   cid  = tc[ti];
        const float bx0 = tb_[ti * 4 + 0], bx1 = tb_[ti * 4 + 1];
        const float bx2 = tb_[ti * 4 + 2], bx3 = tb_[ti * 4 + 3];

        const float tx = bx0 * (float)W, ty = bx1 * (float)H;
        const float tw = bx2 * (float)W, th = bx3 * (float)H;
        const int gx = (int)fminf(fmaxf(tx, 0.f), (float)(W - 1));
        const int gy = (int)fminf(fmaxf(ty, 0.f), (float)(H - 1));
        const int cell = gy * W + gx;

        const float* cvbase = cls_p + (size_t)b * C_CH * HW + cell;

        float rvq = 0.f;
        if (lane < 4) rvq = reg_p[(size_t)(b * 4 + lane) * HW + cell];
        float objq = (lane == 0) ? cvbase[0] : 0.f;

        float fsum = 0.f;
        for (int c = lane; c < NUM_CLASSES; c += 64) {
            float x   = cvbase[(size_t)(c + 1) * HW];
            float tgt = (c == cid) ? 1.f : 0.f;
            float bce = softplusf(x) - x * tgt;
            float p   = sigmoidf_(x);
            float pt  = p * tgt + (1.f - p) * (1.f - tgt);
            float om  = 1.f - pt;
            fsum += 0.25f * om * om * bce;
        }
        for (int off = 32; off > 0; off >>= 1) fsum += __shfl_down(fsum, off, 64);

        float rv0 = __shfl(rvq, 0, 64), rv1 = __shfl(rvq, 1, 64);
        float rv2 = __shfl(rvq, 2, 64), rv3 = __shfl(rvq, 3, 64);

        if (lane == 0) {
            lcv = (fsum * (1.f / (float)NUM_CLASSES)) * mask;
            lo  = softplusf(-objq) * mask;

            float dx = sigmoidf_(rv0), dy = sigmoidf_(rv1);
            float dw = expf(fminf(fmaxf(rv2, -4.f), 4.f));
            float dh = expf(fminf(fmaxf(rv3, -4.f), 4.f));
            float px = (float)gx + dx, py = (float)gy + dy;
            float pb0 = px - dw * 0.5f, pb1 = py - dh * 0.5f, pb2 = px + dw * 0.5f, pb3 = py + dh * 0.5f;
            float tb0 = tx - tw * 0.5f, tb1 = ty - th * 0.5f, tb2 = tx + tw * 0.5f, tb3 = ty + th * 0.5f;
            float s = 0.f, d, a;
            d = pb0 - tb0; a = fabsf(d); s += (a < 1.f) ? 0.5f * d * d : a - 0.5f;
            d = pb1 - tb1; a = fabsf(d); s += (a < 1.f) ? 0.5f * d * d : a - 0.5f;
            d = pb2 - tb2; a = fabsf(d); s += (a < 1.f) ? 0.5f * d * d : a - 0.5f;
            d = pb3 - tb3; a = fabsf(d); s += (a < 1.f) ? 0.5f * d * d : a - 0.5f;
            lb = (s * 0.25f) * mask;
            msum = mask;
        }
    }

    __shared__ float s4[4][4];
    if (lane == 0) { s4[wave][0] = lb; s4[wave][1] = lo; s4[wave][2] = lcv; s4[wave][3] = msum; }
    __syncthreads();
    if (tid < 4) {
        float v = s4[0][tid] + s4[1][tid] + s4[2][tid] + s4[3][tid];
        tpart[((int)blockIdx.x - nbg) * 4 + tid] = v;
    }
}

#define HASH_SZ 8192

__global__ void __launch_bounds__(1024) final_kernel(
    const float* __restrict__ cls_p4, const float* __restrict__ cls_p5,
    const float* __restrict__ t4_box, const float* __restrict__ t4_mask,
    const float* __restrict__ t5_box, const float* __restrict__ t5_mask,
    const float* __restrict__ bgpart, int nbg4, int nbg5,
    const float* __restrict__ tpart, int nT4,
    int B, int T, float* __restrict__ out)
{
    __shared__ unsigned int hash[HASH_SZ];
    __shared__ float red[16][12];
    const int tid = threadIdx.x;
    const int BT = B * T;

    for (int i = tid; i < HASH_SZ; i += 1024) hash[i] = 0u;
    __syncthreads();

    // dedup occupied cells; on first insert, gather softplus(obj) at that cell
    float occ_sp4 = 0.f, occ_c4 = 0.f, occ_sp5 = 0.f, occ_c5 = 0.f;
    for (int g = tid; g < 2 * BT; g += 1024) {
        const int scale = (g >= BT) ? 1 : 0;
        const int ti = scale ? g - BT : g;
        const float* tb_ = scale ? t5_box : t4_box;
        const float* tm  = scale ? t5_mask : t4_mask;
        const float mask = tm[ti];
        if (mask > 0.f) {
            const int b = ti / T;
            const int W = scale ? 40 : 80, H = W;
            const int HW = W * H;
            const float tx = tb_[ti * 4 + 0] * (float)W;
            const float ty = tb_[ti * 4 + 1] * (float)H;
            const int gx = (int)fminf(fmaxf(tx, 0.f), (float)(W - 1));
            const int gy = (int)fminf(fmaxf(ty, 0.f), (float)(H - 1));
            const int cell = gy * W + gx;
            const unsigned int id = ((unsigned)scale << 18) | (unsigned)(b * HW + cell);
            const unsigned int key = id + 1u;
            unsigned int h = (id * 2654435761u) >> 19;  // top 13 bits
            h &= (HASH_SZ - 1);
            for (;;) {
                unsigned int old = atomicCAS(&hash[h], 0u, key);
                if (old == 0u) {
                    const float* cls_p = scale ? cls_p5 : cls_p4;
                    float sp = softplusf(cls_p[(size_t)b * C_CH * HW + cell]);
                    if (scale) { occ_sp5 += sp; occ_c5 += 1.f; }
                    else       { occ_sp4 += sp; occ_c4 += 1.f; }
                    break;
                }
                if (old == key) break;
                h = (h + 1) & (HASH_SZ - 1);
            }
        }
    }

    // strided partial reductions
    float lb = 0.f, lo = 0.f, lc = 0.f, n = 0.f, bg4 = 0.f, bg5 = 0.f;
    for (int i = tid; i < nT4; i += 1024) {
        lb += tpart[i * 4 + 0]; lo += tpart[i * 4 + 1];
        lc += tpart[i * 4 + 2]; n  += tpart[i * 4 + 3];
    }
    for (int i = tid; i < nbg4; i += 1024) bg4 += bgpart[i];
    for (int i = tid; i < nbg5; i += 1024) bg5 += bgpart[nbg4 + i];

    float vals[10] = { lb, lo, lc, n, bg4, bg5, occ_sp4, occ_c4, occ_sp5, occ_c5 };
    #pragma unroll
    for (int k = 0; k < 10; k++) {
        float v = vals[k];
        for (int off = 32; off > 0; off >>= 1) v += __shfl_down(v, off, 64);
        vals[k] = v;
    }
    if ((tid & 63) == 0) {
        #pragma unroll
        for (int k = 0; k < 10; k++) red[tid >> 6][k] = vals[k];
    }
    __syncthreads();
    if (tid == 0) {
        float t[10];
        #pragma unroll
        for (int k = 0; k < 10; k++) {
            float s = 0.f;
            for (int w = 0; w < 16; w++) s += red[w][k];
            t[k] = s;
        }
        float lbt = t[0], lot = t[1], lct = t[2], nt = t[3];
        float bce_bg4 = t[4] - t[6];
        float bce_bg5 = t[5] - t[8];
        float cnt4 = (float)(B * 6400) - t[7];
        float cnt5 = (float)(B * 1600) - t[9];
        lot += 0.05f * ((cnt4 > 0.f) ? bce_bg4 / fmaxf(cnt4, 1.f) : 0.f);
        lot += 0.05f * ((cnt5 > 0.f) ? bce_bg5 / fmaxf(cnt5, 1.f) : 0.f);
        float nd = fmaxf(nt, 1.f);
        if (nt > 0.f) { lbt /= nd; lct /= nd; }
        lot /= fmaxf(nt, 1.f);
        out[0] = 2.0f * lbt + 1.0f * lot + 0.5f * lct;
    }
}

extern "C" void kernel_launch(void* const* d_in, const int* in_sizes, int n_in,
                              void* d_out, int out_size, void* d_ws, size_t ws_size,
                              hipStream_t stream) {
    const float* cls_p4 = (const float*)d_in[0];
    const float* reg_p4 = (const float*)d_in[1];
    const float* cls_p5 = (const float*)d_in[2];
    const float* reg_p5 = (const float*)d_in[3];
    const int*   t4_cls = (const int*)d_in[4];
    const float* t4_box = (const float*)d_in[5];
    const float* t4_mask= (const float*)d_in[6];
    const int*   t5_cls = (const int*)d_in[7];
    const float* t5_box = (const float*)d_in[8];
    const float* t5_mask= (const float*)d_in[9];

    const int B = in_sizes[0] / (C_CH * 6400);   // cls_p4: B x 81 x 80 x 80
    const int T = in_sizes[4] / B;               // t4_cls: B x T
    const int BT = B * T;

    const int nbg4 = B * 25;
    const int nbg5 = B * 7;
    const int nTblk = (2 * BT + 3) / 4;

    float* bgpart = (float*)d_ws;
    float* tpart  = bgpart + (nbg4 + nbg5);

    fused_kernel<<<nbg4 + nbg5 + nTblk, 256, 0, stream>>>(
        cls_p4, reg_p4, cls_p5, reg_p5,
        t4_cls, t4_box, t4_mask, t5_cls, t5_box, t5_mask,
        bgpart, tpart, B, T, nbg4, nbg5);

    final_kernel<<<1, 1024, 0, stream>>>(
        cls_p4, cls_p5, t4_box, t4_mask, t5_box, t5_mask,
        bgpart, nbg4, nbg5, tpart, nTblk, B, T, (float*)d_out);
}

// Round 4
// 125.531 us; speedup vs baseline: 1.1787x; 1.1787x over previous
//
#include <hip/hip_runtime.h>
#include <math.h>

#define NUM_CLASSES 80
#define C_CH (NUM_CLASSES + 1)
#define MAX_T 128   // dedup LDS capacity per wave (T=64 in this problem)

__device__ __forceinline__ float softplusf(float x) {
    return fmaxf(x, 0.f) + log1pf(expf(-fabsf(x)));
}
__device__ __forceinline__ float sigmoidf_(float x) {
    return 1.f / (1.f + expf(-x));
}

// ws layout (floats), all written unconditionally every call (no zeroing):
//   bgpart  : nbg4+nbg5 floats     per-block plane sums of softplus(ch0)
//   tpart   : nTblk*4 floats       {lb, lo, lc, n} per target-block
//   occpart : 2B*2 floats          {occ_softplus_sum, occ_count} per (b,scale)

__global__ void fused_kernel(
    const float* __restrict__ cls_p4, const float* __restrict__ reg_p4,
    const float* __restrict__ cls_p5, const float* __restrict__ reg_p5,
    const int* __restrict__ t4_cls, const float* __restrict__ t4_box, const float* __restrict__ t4_mask,
    const int* __restrict__ t5_cls, const float* __restrict__ t5_box, const float* __restrict__ t5_mask,
    float* __restrict__ bgpart, float* __restrict__ tpart, float* __restrict__ occpart,
    int B, int T, int nbg4, int nbg5, int nTblk)
{
    const int tid  = threadIdx.x;
    const int wave = tid >> 6;
    const int lane = tid & 63;
    const int nbg  = nbg4 + nbg5;
    const int BT   = B * T;

    if ((int)blockIdx.x < nbg) {
        // ---------- role 1: background plane sum of softplus(channel 0) ----------
        const int blk = blockIdx.x;
        float sp = 0.f;
        if (blk < nbg4) {
            int b = blk / 25, j = blk - b * 25;          // 6400/256 = 25 blocks/image
            int cell = j * 256 + tid;
            sp = softplusf(cls_p4[(size_t)b * (C_CH * 6400) + cell]);
        } else {
            int o = blk - nbg4;
            int b = o / 7, j = o - b * 7;                // ceil(1600/256) = 7 blocks/image
            int cell = j * 256 + tid;
            if (cell < 1600)
                sp = softplusf(cls_p5[(size_t)b * (C_CH * 1600) + cell]);
        }
        for (int off = 32; off > 0; off >>= 1) sp += __shfl_down(sp, off, 64);
        __shared__ float ss[4];
        if (lane == 0) ss[wave] = sp;
        __syncthreads();
        if (tid == 0) bgpart[blockIdx.x] = ss[0] + ss[1] + ss[2] + ss[3];
        return;
    }

    if ((int)blockIdx.x < nbg + nTblk) {
        // ---------- role 2: per-target losses, 4 targets/block (one per wave) ----------
        const int tg = ((int)blockIdx.x - nbg) * 4 + wave;
        float lb = 0.f, lo = 0.f, lcv = 0.f, msum = 0.f;

        if (tg < 2 * BT) {
            const int scale = (tg >= BT) ? 1 : 0;
            const int ti = scale ? tg - BT : tg;
            const int b = ti / T;

            const float* cls_p; const float* reg_p; const int* tc; const float* tb_; const float* tm;
            int H, W;
            if (!scale) { cls_p = cls_p4; reg_p = reg_p4; tc = t4_cls; tb_ = t4_box; tm = t4_mask; H = 80; W = 80; }
            else        { cls_p = cls_p5; reg_p = reg_p5; tc = t5_cls; tb_ = t5_box; tm = t5_mask; H = 40; W = 40; }
            const int HW = H * W;

            const float mask = tm[ti];
            const int   cid  = tc[ti];
            const float bx0 = tb_[ti * 4 + 0], bx1 = tb_[ti * 4 + 1];
            const float bx2 = tb_[ti * 4 + 2], bx3 = tb_[ti * 4 + 3];

            const float tx = bx0 * (float)W, ty = bx1 * (float)H;
            const float tw = bx2 * (float)W, th = bx3 * (float)H;
            const int gx = (int)fminf(fmaxf(tx, 0.f), (float)(W - 1));
            const int gy = (int)fminf(fmaxf(ty, 0.f), (float)(H - 1));
            const int cell = gy * W + gx;

            const float* cvbase = cls_p + (size_t)b * C_CH * HW + cell;

            float rvq = 0.f;
            if (lane < 4) rvq = reg_p[(size_t)(b * 4 + lane) * HW + cell];
            float objq = (lane == 0) ? cvbase[0] : 0.f;

            float fsum = 0.f;
            for (int c = lane; c < NUM_CLASSES; c += 64) {
                float x   = cvbase[(size_t)(c + 1) * HW];
                float tgt = (c == cid) ? 1.f : 0.f;
                float bce = softplusf(x) - x * tgt;
                float p   = sigmoidf_(x);
                float pt  = p * tgt + (1.f - p) * (1.f - tgt);
                float om  = 1.f - pt;
                fsum += 0.25f * om * om * bce;
            }
            for (int off = 32; off > 0; off >>= 1) fsum += __shfl_down(fsum, off, 64);

            float rv0 = __shfl(rvq, 0, 64), rv1 = __shfl(rvq, 1, 64);
            float rv2 = __shfl(rvq, 2, 64), rv3 = __shfl(rvq, 3, 64);

            if (lane == 0) {
                lcv = (fsum * (1.f / (float)NUM_CLASSES)) * mask;
                lo  = softplusf(-objq) * mask;

                float dx = sigmoidf_(rv0), dy = sigmoidf_(rv1);
                float dw = expf(fminf(fmaxf(rv2, -4.f), 4.f));
                float dh = expf(fminf(fmaxf(rv3, -4.f), 4.f));
                float px = (float)gx + dx, py = (float)gy + dy;
                float pb0 = px - dw * 0.5f, pb1 = py - dh * 0.5f, pb2 = px + dw * 0.5f, pb3 = py + dh * 0.5f;
                float tb0 = tx - tw * 0.5f, tb1 = ty - th * 0.5f, tb2 = tx + tw * 0.5f, tb3 = ty + th * 0.5f;
                float s = 0.f, d, a;
                d = pb0 - tb0; a = fabsf(d); s += (a < 1.f) ? 0.5f * d * d : a - 0.5f;
                d = pb1 - tb1; a = fabsf(d); s += (a < 1.f) ? 0.5f * d * d : a - 0.5f;
                d = pb2 - tb2; a = fabsf(d); s += (a < 1.f) ? 0.5f * d * d : a - 0.5f;
                d = pb3 - tb3; a = fabsf(d); s += (a < 1.f) ? 0.5f * d * d : a - 0.5f;
                lb = (s * 0.25f) * mask;
                msum = mask;
            }
        }

        __shared__ float s4[4][4];
        if (lane == 0) { s4[wave][0] = lb; s4[wave][1] = lo; s4[wave][2] = lcv; s4[wave][3] = msum; }
        __syncthreads();
        if (tid < 4) {
            float v = s4[0][tid] + s4[1][tid] + s4[2][tid] + s4[3][tid];
            tpart[((int)blockIdx.x - nbg) * 4 + tid] = v;
        }
        return;
    }

    // ---------- role 3: per-(image,scale) occupied-cell dedup + obj gather ----------
    // pair p in [0, 2B): scale = p/B, b = p%B. One wave per pair.
    {
        __shared__ unsigned int cells[4][MAX_T];
        const int p = ((int)blockIdx.x - nbg - nTblk) * 4 + wave;
        float osp = 0.f, ocnt = 0.f;
        bool valid_pair = (p < 2 * B) && (T <= MAX_T);
        int scale = 0, b = 0;
        const float* tb_ = nullptr; const float* tm = nullptr;
        int W = 80, HW = 6400;
        if (valid_pair) {
            scale = p / B; b = p - scale * B;
            tb_ = scale ? t5_box : t4_box;
            tm  = scale ? t5_mask : t4_mask;
            W = scale ? 40 : 80; HW = W * W;
            for (int i = lane; i < T; i += 64) {
                const int ti = b * T + i;
                unsigned int cellv = 0xFFFFFFFFu;
                if (tm[ti] > 0.f) {
                    const float tx = tb_[ti * 4 + 0] * (float)W;
                    const float ty = tb_[ti * 4 + 1] * (float)W;
                    const int gx = (int)fminf(fmaxf(tx, 0.f), (float)(W - 1));
                    const int gy = (int)fminf(fmaxf(ty, 0.f), (float)(W - 1));
                    cellv = (unsigned)(gy * W + gx);
                }
                cells[wave][i] = cellv;
            }
        }
        __syncthreads();
        if (valid_pair) {
            const float* cls_p = scale ? cls_p5 : cls_p4;
            for (int i = lane; i < T; i += 64) {
                unsigned int cv = cells[wave][i];
                if (cv != 0xFFFFFFFFu) {
                    bool first = true;
                    for (int j = 0; j < i; j++)
                        if (cells[wave][j] == cv) { first = false; break; }
                    if (first) {
                        osp  += softplusf(cls_p[(size_t)b * C_CH * HW + (int)cv]);
                        ocnt += 1.f;
                    }
                }
            }
        }
        for (int off = 32; off > 0; off >>= 1) {
            osp  += __shfl_down(osp,  off, 64);
            ocnt += __shfl_down(ocnt, off, 64);
        }
        if (lane == 0 && p < 2 * B) {
            occpart[p * 2]     = osp;
            occpart[p * 2 + 1] = ocnt;
        }
    }
}

__global__ void __launch_bounds__(256) final_kernel(
    const float* __restrict__ bgpart, int nbg4, int nbg5,
    const float* __restrict__ tpart, int nTblk,
    const float* __restrict__ occpart,
    int B, float* __restrict__ out)
{
    const int tid = threadIdx.x;
    float lb = 0.f, lo = 0.f, lc = 0.f, n = 0.f;
    float bg4 = 0.f, bg5 = 0.f, o4 = 0.f, c4 = 0.f, o5 = 0.f, c5 = 0.f;

    for (int i = tid; i < nTblk; i += 256) {
        lb += tpart[i * 4 + 0]; lo += tpart[i * 4 + 1];
        lc += tpart[i * 4 + 2]; n  += tpart[i * 4 + 3];
    }
    for (int i = tid; i < nbg4; i += 256) bg4 += bgpart[i];
    for (int i = tid; i < nbg5; i += 256) bg5 += bgpart[nbg4 + i];
    for (int p = tid; p < 2 * B; p += 256) {
        if (p < B) { o4 += occpart[p * 2]; c4 += occpart[p * 2 + 1]; }
        else       { o5 += occpart[p * 2]; c5 += occpart[p * 2 + 1]; }
    }

    __shared__ float red[4][10];
    float vals[10] = { lb, lo, lc, n, bg4, bg5, o4, c4, o5, c5 };
    #pragma unroll
    for (int k = 0; k < 10; k++) {
        float v = vals[k];
        for (int off = 32; off > 0; off >>= 1) v += __shfl_down(v, off, 64);
        vals[k] = v;
    }
    if ((tid & 63) == 0) {
        #pragma unroll
        for (int k = 0; k < 10; k++) red[tid >> 6][k] = vals[k];
    }
    __syncthreads();
    if (tid == 0) {
        float t[10];
        #pragma unroll
        for (int k = 0; k < 10; k++)
            t[k] = red[0][k] + red[1][k] + red[2][k] + red[3][k];

        float lbt = t[0], lot = t[1], lct = t[2], nt = t[3];
        float bce_bg4 = t[4] - t[6];
        float bce_bg5 = t[5] - t[8];
        float cnt4 = (float)(B * 6400) - t[7];
        float cnt5 = (float)(B * 1600) - t[9];
        lot += 0.05f * ((cnt4 > 0.f) ? bce_bg4 / fmaxf(cnt4, 1.f) : 0.f);
        lot += 0.05f * ((cnt5 > 0.f) ? bce_bg5 / fmaxf(cnt5, 1.f) : 0.f);
        float nd = fmaxf(nt, 1.f);
        if (nt > 0.f) { lbt /= nd; lct /= nd; }
        lot /= fmaxf(nt, 1.f);
        out[0] = 2.0f * lbt + 1.0f * lot + 0.5f * lct;
    }
}

extern "C" void kernel_launch(void* const* d_in, const int* in_sizes, int n_in,
                              void* d_out, int out_size, void* d_ws, size_t ws_size,
                              hipStream_t stream) {
    const float* cls_p4 = (const float*)d_in[0];
    const float* reg_p4 = (const float*)d_in[1];
    const float* cls_p5 = (const float*)d_in[2];
    const float* reg_p5 = (const float*)d_in[3];
    const int*   t4_cls = (const int*)d_in[4];
    const float* t4_box = (const float*)d_in[5];
    const float* t4_mask= (const float*)d_in[6];
    const int*   t5_cls = (const int*)d_in[7];
    const float* t5_box = (const float*)d_in[8];
    const float* t5_mask= (const float*)d_in[9];

    const int B = in_sizes[0] / (C_CH * 6400);   // cls_p4: B x 81 x 80 x 80
    const int T = in_sizes[4] / B;               // t4_cls: B x T
    const int BT = B * T;

    const int nbg4  = B * 25;
    const int nbg5  = B * 7;
    const int nTblk = (2 * BT + 3) / 4;          // 4 targets per block
    const int ndblk = (2 * B + 3) / 4;           // 4 (b,scale) pairs per block

    float* bgpart  = (float*)d_ws;
    float* tpart   = bgpart + (nbg4 + nbg5);
    float* occpart = tpart + (size_t)nTblk * 4;

    fused_kernel<<<nbg4 + nbg5 + nTblk + ndblk, 256, 0, stream>>>(
        cls_p4, reg_p4, cls_p5, reg_p5,
        t4_cls, t4_box, t4_mask, t5_cls, t5_box, t5_mask,
        bgpart, tpart, occpart, B, T, nbg4, nbg5, nTblk);

    final_kernel<<<1, 256, 0, stream>>>(bgpart, nbg4, nbg5, tpart, nTblk,
                                        occpart, B, (float*)d_out);
}